// Round 14
// baseline (395.451 us; speedup 1.0000x reference)
//
#include <hip/hip_runtime.h>
#include <hip/hip_bf16.h>

typedef __attribute__((ext_vector_type(8))) short short8;
typedef __attribute__((ext_vector_type(16))) float f32x16;

typedef const __attribute__((address_space(1))) unsigned int* gas1_t;
typedef __attribute__((address_space(3))) unsigned int* las3_t;

__device__ __forceinline__ unsigned short f2bf(float x) {
    unsigned int u = __float_as_uint(x);
    u = (u + 0x7fffu + ((u >> 16) & 1u)) >> 16;   // RNE
    return (unsigned short)u;
}

__device__ __forceinline__ int4 pack8(const unsigned short* u) {
    int4 p;
    p.x = (int)((unsigned)u[0] | ((unsigned)u[1] << 16));
    p.y = (int)((unsigned)u[2] | ((unsigned)u[3] << 16));
    p.z = (int)((unsigned)u[4] | ((unsigned)u[5] << 16));
    p.w = (int)((unsigned)u[6] | ((unsigned)u[7] << 16));
    return p;
}

__device__ __forceinline__ void gld_lds16(const void* g, void* l) {
    __builtin_amdgcn_global_load_lds((gas1_t)g, (las3_t)l, 16, 0, 0);
}

// ---------------------------------------------------------------------------
// s[cv][b][c] = 1 + PixelNorm(EqualLinear(latent)); grid 16, block 256
__global__ void style_kernel(const float* __restrict__ latent,
                             const float* __restrict__ elw0, const float* __restrict__ elb0,
                             const float* __restrict__ elw1, const float* __restrict__ elb1,
                             float* __restrict__ s_arr) {
    const int cv = blockIdx.x >> 3;
    const int b  = blockIdx.x & 7;
    const int c  = threadIdx.x;
    const float* elw = cv ? elw1 : elw0;
    const float* elb = cv ? elb1 : elb0;

    __shared__ float lat[512];
    lat[c] = latent[b * 512 + c];
    lat[c + 256] = latent[b * 512 + c + 256];
    __syncthreads();

    float accv = 0.f;
    const float* wrow = elw + (size_t)c * 512;
#pragma unroll 8
    for (int k = 0; k < 512; ++k) accv += lat[k] * wrow[k];
    const float lin = accv * 0.04419417382415922f + elb[c];

    float sq = lin * lin;
#pragma unroll
    for (int off = 32; off >= 1; off >>= 1) sq += __shfl_xor(sq, off);
    __shared__ float wsum[4];
    if ((threadIdx.x & 63) == 0) wsum[threadIdx.x >> 6] = sq;
    __syncthreads();
    const float total = wsum[0] + wsum[1] + wsum[2] + wsum[3];
    const float s = 1.0f + lin * rsqrtf(total * (1.0f / 256.0f) + 1e-8f);
    s_arr[(cv * 8 + b) * 256 + c] = s;
}

// wsq[cv][o][c] = sum_t (w*sc)^2 ; grid 512, block 256
__global__ void wsq_kernel(const float* __restrict__ w0, const float* __restrict__ w1,
                           float* __restrict__ wsq) {
    const int cv = blockIdx.x >> 8;
    const int o  = blockIdx.x & 255;
    const int c  = threadIdx.x;
    const float* w = cv ? w1 : w0;
    const size_t base = ((size_t)o * 256 + c) * 9;
    float ssum = 0.f;
#pragma unroll
    for (int t = 0; t < 9; ++t) { float v = w[base + t]; ssum += v * v; }
    wsq[((size_t)cv * 256 + o) * 256 + c] = ssum * (2.0f / 2304.0f);
}

// d[cv][b][o] = rsqrt(sum_c s^2 * wsq + 1e-5) ; grid 16, block 256
__global__ void demod_kernel(const float* __restrict__ s_arr, const float* __restrict__ wsq,
                             float* __restrict__ d_arr) {
    const int cv = blockIdx.x >> 3;
    const int b  = blockIdx.x & 7;
    const int o  = threadIdx.x;
    __shared__ float ss[256];
    float sv = s_arr[(cv * 8 + b) * 256 + o];
    ss[o] = sv * sv;
    __syncthreads();
    const float* wrow = wsq + ((size_t)cv * 256 + o) * 256;
    float accv = 0.f;
#pragma unroll 8
    for (int c = 0; c < 256; ++c) accv += ss[c] * wrow[c];
    d_arr[(cv * 8 + b) * 256 + o] = rsqrtf(accv + 1e-5f);
}

// wmod[b][cc][t] slab (8192 elems) laid out [k-octet 0..3][o 0..255][8 ch]
// -> lane-contiguous 16B fragments. grid (18432,2), block 256
__global__ void fold_kernel(const float* __restrict__ w0, const float* __restrict__ w1,
                            const float* __restrict__ s_arr, const float* __restrict__ d_arr,
                            unsigned short* __restrict__ wm0, unsigned short* __restrict__ wm1) {
    const int cv = blockIdx.y;
    const int e  = blockIdx.x * 256 + threadIdx.x;       // 0 .. 4718591
    const float* w = cv ? w1 : w0;
    unsigned short* wm = cv ? wm1 : wm0;
    const int slab = e >> 13;            // 0..575  = ((b*8)+cc)*9 + t
    const int idx  = e & 8191;
    const int b  = slab / 72;
    const int s2 = slab - b * 72;
    const int cc = s2 / 9;
    const int t  = s2 - cc * 9;
    const int o  = idx >> 5;
    const int c5 = idx & 31;
    const int c  = cc * 32 + c5;
    const float val = w[((size_t)o * 256 + c) * 9 + t] * 0.029462782549439483f  // sqrt(2/2304)
                    * s_arr[(cv * 8 + b) * 256 + c] * d_arr[(cv * 8 + b) * 256 + o];
    wm[((size_t)slab << 13) + (c5 >> 3) * 2048 + o * 8 + (c5 & 7)] = f2bf(val);
}

// x (fp32 NCHW) -> xq (bf16 NHWC8): [b][g=32][h][w][8ch]; grid 32768, block 256
__global__ void convert_kernel(const float* __restrict__ x, unsigned short* __restrict__ xq) {
    const int blk = blockIdx.x;
    const int hh  = blk & 127;
    const int bg_ = blk >> 7;
    const int g   = bg_ & 31;
    const int b   = bg_ >> 5;
    __shared__ float sx[8][128];
    const int tid = threadIdx.x;
#pragma unroll
    for (int i = 0; i < 4; ++i) {
        const int idx = tid + i * 256;
        const int c8 = idx >> 7, p = idx & 127;
        sx[c8][p] = x[(((size_t)b * 256 + g * 8 + c8) * 128 + hh) * 128 + p];
    }
    __syncthreads();
    if (tid < 128) {
        const int p = tid;
        unsigned short u[8];
#pragma unroll
        for (int j = 0; j < 8; ++j) u[j] = f2bf(sx[j][p]);
        *(int4*)(xq + ((((size_t)b * 32 + g) * 128 + hh) * 128 + p) * 8) = pack8(u);
    }
}

// ---------------------------------------------------------------------------
// Modulated conv, implicit GEMM: M=256 (o), N=256 (2 rows x 128 px), K=2304.
// 16 waves (1024 thr), wave tile 64o x 64px, 4 waves/SIMD (R13, verified).
// Region schedule (3 taps/barrier), A region-double-buffered, B split-staged
// across barriers (R12 pattern). NEW in R14: s_setprio(1) around each tap's
// MFMA cluster -- T5's regime (multi-wave role-split between barrier-free
// taps) is present at 4 waves/SIMD (m218b/m224: +21-39% in this regime).
// Fused: +bias, leaky*sqrt2, PixelNorm; !FINAL_OUT -> NHWC8 bf16, else fp32 NCHW.
template<bool FINAL_OUT>
__global__ __launch_bounds__(1024, 4) void conv_kernel(
    const unsigned short* __restrict__ in_q, const unsigned short* __restrict__ wmod,
    const float* __restrict__ bias, const unsigned short* __restrict__ zpg,
    void* __restrict__ out_v) {

    // [0,98304)       A: 2 region-buffers x 3 slabs x 16KB
    // [98304,131072)  B: 4 rows x 4 koct x 128 px x 16B (single buffer)
    // [131072,131136) zero slot   [131136,132160) bias   [132160,136256) red
    __shared__ __align__(16) char lds[136256];

    const int tid  = threadIdx.x;
    const int b    = blockIdx.x & 7;          // XCD-affine (image b -> XCD b)
    const int rp   = blockIdx.x >> 3;         // 0..63 row pair
    const int h0   = rp * 2;
    const int lane = tid & 63;
    const int wr   = tid >> 6;                // 0..15
    const int wm   = wr & 3;                  // o-quarter (64 o's)
    const int wn2  = (wr >> 2) & 1;           // px half
    const int wrow = wr >> 3;                 // row within pair
    const int l31  = lane & 31;
    const int khg  = lane >> 5;               // k-octet half

    float* sbias = (float*)(lds + 131136);
    if (tid < 256) sbias[tid] = bias[tid];
    if (tid < 4)   *(int4*)(lds + 131072 + tid * 16) = (int4){0, 0, 0, 0};

    // A frag byte offsets within a slab: [koct][o][16B]
    int aoff[2][2];
#pragma unroll
    for (int mb = 0; mb < 2; ++mb)
#pragma unroll
        for (int kh = 0; kh < 2; ++kh)
            aoff[mb][kh] = ((khg + 2 * kh) * 256 + wm * 64 + mb * 32 + l31) * 16;
    // B frag lane bases (add (wrow+dy)*8192 + (dx-1)*16 per tap)
    int boff[2][2];
#pragma unroll
    for (int nb = 0; nb < 2; ++nb)
#pragma unroll
        for (int kh = 0; kh < 2; ++kh)
            boff[nb][kh] = 98304 + (khg + 2 * kh) * 2048
                         + (wn2 * 64 + nb * 32 + l31) * 16;
    const bool isL = (wn2 == 0) && (l31 == 0);
    const bool isR = (wn2 == 1) && (l31 == 31);

    const unsigned short* wmb = wmod + (size_t)b * 589824;
    const unsigned short* xqb = in_q + (size_t)b * 4194304;   // [32][128][128][8]

    // stage 3 slabs (one region, 48KB) into region buffer nbuf; 3 gld/wave
    auto issueA3 = [&](const char* src, int nbuf) {
        char* db = lds + nbuf * 49152 + wr * 1024;           // wave-uniform base
        const char* s = src + wr * 1024 + lane * 16;
#pragma unroll
        for (int j = 0; j < 3; ++j)
            gld_lds16(s + j * 16384, db + j * 16384);
    };

    // stage B rows [r0, r1) of channel-block cc; wave wr>>2 owns row, wr&3 koct
    auto issueBrows = [&](int cc, int r0, int r1) {
        const int row = wr >> 2;              // 0..3 (wave-uniform)
        if (row < r0 || row >= r1) return;
        const int koct = wr & 3;
        char* dst = lds + 98304 + row * 8192 + koct * 2048;
        const int hin = h0 - 1 + row;
        if ((unsigned)hin < 128u) {
            const unsigned short* src = xqb
                + ((size_t)(cc * 4 + koct) * 128 + hin) * 1024 + lane * 8;
            gld_lds16(src,       dst);
            gld_lds16(src + 512, dst + 1024);     // px + 64
        } else {
            gld_lds16(zpg, dst);
            gld_lds16(zpg, dst + 1024);
        }
    };

    f32x16 acc[2][2];
#pragma unroll
    for (int mb = 0; mb < 2; ++mb)
#pragma unroll
        for (int nb = 0; nb < 2; ++nb)
#pragma unroll
            for (int r = 0; r < 16; ++r) acc[mb][nb][r] = 0.f;

    // prologue: region 0 A + all 4 B rows of cc0; full drain via __syncthreads
    issueA3((const char*)wmb, 0);
    issueBrows(0, 0, 4);
    __syncthreads();

    const char* gA = (const char*)wmb + 49152;   // region 1 onward
#pragma unroll 1
    for (int cc = 0; cc < 8; ++cc) {
#pragma unroll
        for (int r = 0; r < 3; ++r) {             // region = dy row = 3 taps
            const int g = cc * 3 + r;
            // top of r==0 (after cc-boundary barrier): rows 2,3 of THIS cc
            // (r==0 reads only rows 0,1 -> disjoint; drained at r==0's end).
            if (r == 0 && cc > 0) issueBrows(cc, 2, 4);
            // top of cc's LAST region: rows 0,1 of cc+1 (readers done at the
            // r==1-end barrier).
            if (r == 2 && cc < 7) issueBrows(cc + 1, 0, 2);
            if (g < 23) { issueA3(gA, (g + 1) & 1); gA += 49152; }
            const char* Ac = lds + (g & 1) * 49152;
#pragma unroll
            for (int i = 0; i < 3; ++i) {         // tap: dx = i
                short8 af[2][2], bf[2][2];
#pragma unroll
                for (int mb = 0; mb < 2; ++mb)
#pragma unroll
                    for (int kh = 0; kh < 2; ++kh)
                        af[mb][kh] = *(const short8*)(Ac + i * 16384 + aoff[mb][kh]);
                const int badd = (wrow + r) * 8192 + (i - 1) * 16;
#pragma unroll
                for (int nb = 0; nb < 2; ++nb)
#pragma unroll
                    for (int kh = 0; kh < 2; ++kh) {
                        int off = boff[nb][kh] + badd;
                        if (i == 0 && nb == 0) off = isL ? 131072 : off;
                        if (i == 2 && nb == 1) off = isR ? 131072 : off;
                        bf[nb][kh] = *(const short8*)(lds + off);
                    }
                __builtin_amdgcn_s_setprio(1);    // T5: bias scheduler toward
#pragma unroll                                     // MFMA-ready waves (4 w/SIMD)
                for (int kh = 0; kh < 2; ++kh)
#pragma unroll
                    for (int mb = 0; mb < 2; ++mb)
#pragma unroll
                        for (int nb = 0; nb < 2; ++nb)
                            acc[mb][nb] = __builtin_amdgcn_mfma_f32_32x32x16_bf16(
                                af[mb][kh], bf[nb][kh], acc[mb][nb], 0, 0, 0);
                __builtin_amdgcn_s_setprio(0);
            }
            // region end: full drain (A(g+1)/B rows in flight under 24 MFMAs)
            asm volatile("s_waitcnt vmcnt(0) lgkmcnt(0)" ::: "memory");
            __builtin_amdgcn_sched_barrier(0);
            __builtin_amdgcn_s_barrier();
        }
    }

    // ---------------- epilogue: bias + leaky*sqrt2 + PixelNorm ----------------
    float psum[2] = {0.f, 0.f};
    const float actGain = 1.4142135623730951f;
#pragma unroll
    for (int mb = 0; mb < 2; ++mb)
#pragma unroll
        for (int rg = 0; rg < 16; ++rg) {
            const int row = (rg & 3) + 8 * (rg >> 2) + 4 * khg;
            const float bo = sbias[wm * 64 + mb * 32 + row];
#pragma unroll
            for (int nb = 0; nb < 2; ++nb) {
                float v = acc[mb][nb][rg] + bo;
                v = (v > 0.f ? v : 0.2f * v) * actGain;
                acc[mb][nb][rg] = v;
                psum[nb] += v * v;
            }
        }
    psum[0] += __shfl_xor(psum[0], 32);
    psum[1] += __shfl_xor(psum[1], 32);
    float* red = (float*)(lds + 132160);      // [(wrow*2+wn2)*4+wm][64 px]
    const int rslot = (wrow * 2 + wn2) * 4 + wm;
    if (lane < 32) {
        red[rslot * 64 + l31]      = psum[0];
        red[rslot * 64 + 32 + l31] = psum[1];
    }
    __syncthreads();
    float rs[2];
#pragma unroll
    for (int nb = 0; nb < 2; ++nb) {
        const int p = nb * 32 + l31;
        const int base = (wrow * 2 + wn2) * 4;
        const float ssum = red[(base + 0) * 64 + p] + red[(base + 1) * 64 + p]
                         + red[(base + 2) * 64 + p] + red[(base + 3) * 64 + p];
        rs[nb] = rsqrtf(ssum * (1.0f / 256.0f) + 1e-8f);
    }

    const int h = h0 + wrow;
    if (FINAL_OUT) {
        float* outF = (float*)out_v;
#pragma unroll
        for (int mb = 0; mb < 2; ++mb)
#pragma unroll
            for (int rg = 0; rg < 16; ++rg) {
                const int row = (rg & 3) + 8 * (rg >> 2) + 4 * khg;
                const int o = wm * 64 + mb * 32 + row;
                const size_t rb = (((size_t)b * 256 + o) * 128 + h) * 128 + wn2 * 64;
#pragma unroll
                for (int nb = 0; nb < 2; ++nb)
                    outF[rb + nb * 32 + l31] = acc[mb][nb][rg] * rs[nb];
            }
    } else {
        // per-wave transpose 64o x 64px -> NHWC8 bf16, fully unrolled (rule #20)
        unsigned short* outB = (unsigned short*)out_v;
        char* wreg = lds + wr * 4096;         // [64 px][32 o] bf16, chunk-swizzled
#pragma unroll
        for (int mb = 0; mb < 2; ++mb) {
#pragma unroll
            for (int rg = 0; rg < 16; rg += 2) {
                const int row = (rg & 3) + 8 * (rg >> 2) + 4 * khg;   // even, 0..31
#pragma unroll
                for (int nb = 0; nb < 2; ++nb) {
                    const int pxl = nb * 32 + l31;
                    const unsigned lo = f2bf(acc[mb][nb][rg]     * rs[nb]);
                    const unsigned hi = f2bf(acc[mb][nb][rg + 1] * rs[nb]);
                    *(unsigned int*)(wreg + pxl * 64 + (((row >> 3) ^ (pxl & 3)) << 4)
                                     + (row & 7) * 2) = lo | (hi << 16);
                }
            }
            asm volatile("s_waitcnt lgkmcnt(0)" ::: "memory");
#pragma unroll
            for (int oc = 0; oc < 4; ++oc) {
                const int pxl = lane;
                const int4 v = *(const int4*)(wreg + pxl * 64 + ((oc ^ (pxl & 3)) << 4));
                const int gch = wm * 8 + mb * 4 + oc;
                *(int4*)(outB + ((((size_t)b * 32 + gch) * 128 + h) * 128
                                 + wn2 * 64 + pxl) * 8) = v;
            }
            asm volatile("s_waitcnt lgkmcnt(0)" ::: "memory");
        }
    }
}

// ---------------------------------------------------------------------------
extern "C" void kernel_launch(void* const* d_in, const int* in_sizes, int n_in,
                              void* d_out, int out_size, void* d_ws, size_t ws_size,
                              hipStream_t stream) {
    (void)in_sizes; (void)n_in; (void)out_size; (void)ws_size;
    const float* x      = (const float*)d_in[0];
    const float* latent = (const float*)d_in[1];
    const float* w0     = (const float*)d_in[2];
    const float* b0     = (const float*)d_in[3];
    const float* el0w   = (const float*)d_in[4];
    const float* el0b   = (const float*)d_in[5];
    const float* w1     = (const float*)d_in[6];
    const float* b1     = (const float*)d_in[7];
    const float* el1w   = (const float*)d_in[8];
    const float* el1b   = (const float*)d_in[9];

    char* ws = (char*)d_ws;
    float* s_arr = (float*)ws;                                   // 16 KB
    float* d_arr = (float*)(ws + 16384);                         // 16 KB
    float* wsq   = (float*)(ws + 32768);                         // 512 KB (reused as zero page)
    unsigned short* zpg = (unsigned short*)(ws + 32768);         // 256 B zeros (after demod)
    unsigned short* wm0 = (unsigned short*)(ws + 557056);        // 9.4 MB
    unsigned short* wm1 = (unsigned short*)(ws + 9994240);       // 9.4 MB
    unsigned short* xq  = (unsigned short*)(ws + 19431424);      // 67 MB
    unsigned short* tmp = (unsigned short*)(ws + 86540288);      // 67 MB

    style_kernel<<<16, 256, 0, stream>>>(latent, el0w, el0b, el1w, el1b, s_arr);
    wsq_kernel<<<512, 256, 0, stream>>>(w0, w1, wsq);
    demod_kernel<<<16, 256, 0, stream>>>(s_arr, wsq, d_arr);
    hipMemsetAsync(zpg, 0, 256, stream);   // wsq no longer needed; reuse as zero page
    fold_kernel<<<dim3(18432, 2), 256, 0, stream>>>(w0, w1, s_arr, d_arr, wm0, wm1);
    convert_kernel<<<32768, 256, 0, stream>>>(x, xq);

    conv_kernel<false><<<512, 1024, 0, stream>>>(xq, wm0, b0, zpg, tmp);
    conv_kernel<true><<<512, 1024, 0, stream>>>(tmp, wm1, b1, zpg, d_out);
}

// Round 15
// 394.351 us; speedup vs baseline: 1.0028x; 1.0028x over previous
//
#include <hip/hip_runtime.h>
#include <hip/hip_bf16.h>

typedef __attribute__((ext_vector_type(8))) short short8;
typedef __attribute__((ext_vector_type(16))) float f32x16;

typedef const __attribute__((address_space(1))) unsigned int* gas1_t;
typedef __attribute__((address_space(3))) unsigned int* las3_t;

__device__ __forceinline__ unsigned short f2bf(float x) {
    unsigned int u = __float_as_uint(x);
    u = (u + 0x7fffu + ((u >> 16) & 1u)) >> 16;   // RNE
    return (unsigned short)u;
}

__device__ __forceinline__ int4 pack8(const unsigned short* u) {
    int4 p;
    p.x = (int)((unsigned)u[0] | ((unsigned)u[1] << 16));
    p.y = (int)((unsigned)u[2] | ((unsigned)u[3] << 16));
    p.z = (int)((unsigned)u[4] | ((unsigned)u[5] << 16));
    p.w = (int)((unsigned)u[6] | ((unsigned)u[7] << 16));
    return p;
}

__device__ __forceinline__ void gld_lds16(const void* g, void* l) {
    __builtin_amdgcn_global_load_lds((gas1_t)g, (las3_t)l, 16, 0, 0);
}

// ---------------------------------------------------------------------------
// s[cv][b][c] = 1 + PixelNorm(EqualLinear(latent)); grid 16, block 256
__global__ void style_kernel(const float* __restrict__ latent,
                             const float* __restrict__ elw0, const float* __restrict__ elb0,
                             const float* __restrict__ elw1, const float* __restrict__ elb1,
                             float* __restrict__ s_arr) {
    const int cv = blockIdx.x >> 3;
    const int b  = blockIdx.x & 7;
    const int c  = threadIdx.x;
    const float* elw = cv ? elw1 : elw0;
    const float* elb = cv ? elb1 : elb0;

    __shared__ float lat[512];
    lat[c] = latent[b * 512 + c];
    lat[c + 256] = latent[b * 512 + c + 256];
    __syncthreads();

    float accv = 0.f;
    const float* wrow = elw + (size_t)c * 512;
#pragma unroll 8
    for (int k = 0; k < 512; ++k) accv += lat[k] * wrow[k];
    const float lin = accv * 0.04419417382415922f + elb[c];

    float sq = lin * lin;
#pragma unroll
    for (int off = 32; off >= 1; off >>= 1) sq += __shfl_xor(sq, off);
    __shared__ float wsum[4];
    if ((threadIdx.x & 63) == 0) wsum[threadIdx.x >> 6] = sq;
    __syncthreads();
    const float total = wsum[0] + wsum[1] + wsum[2] + wsum[3];
    const float s = 1.0f + lin * rsqrtf(total * (1.0f / 256.0f) + 1e-8f);
    s_arr[(cv * 8 + b) * 256 + c] = s;
}

// wsq[cv][o][c] = sum_t (w*sc)^2 ; grid 512, block 256
__global__ void wsq_kernel(const float* __restrict__ w0, const float* __restrict__ w1,
                           float* __restrict__ wsq) {
    const int cv = blockIdx.x >> 8;
    const int o  = blockIdx.x & 255;
    const int c  = threadIdx.x;
    const float* w = cv ? w1 : w0;
    const size_t base = ((size_t)o * 256 + c) * 9;
    float ssum = 0.f;
#pragma unroll
    for (int t = 0; t < 9; ++t) { float v = w[base + t]; ssum += v * v; }
    wsq[((size_t)cv * 256 + o) * 256 + c] = ssum * (2.0f / 2304.0f);
}

// d[cv][b][o] = rsqrt(sum_c s^2 * wsq + 1e-5) ; grid 16, block 256
__global__ void demod_kernel(const float* __restrict__ s_arr, const float* __restrict__ wsq,
                             float* __restrict__ d_arr) {
    const int cv = blockIdx.x >> 3;
    const int b  = blockIdx.x & 7;
    const int o  = threadIdx.x;
    __shared__ float ss[256];
    float sv = s_arr[(cv * 8 + b) * 256 + o];
    ss[o] = sv * sv;
    __syncthreads();
    const float* wrow = wsq + ((size_t)cv * 256 + o) * 256;
    float accv = 0.f;
#pragma unroll 8
    for (int c = 0; c < 256; ++c) accv += ss[c] * wrow[c];
    d_arr[(cv * 8 + b) * 256 + o] = rsqrtf(accv + 1e-5f);
}

// wmod[b][cc][t] slab (8192 elems) laid out [k-octet 0..3][o 0..255][8 ch]
// -> lane-contiguous 16B fragments. grid (18432,2), block 256
__global__ void fold_kernel(const float* __restrict__ w0, const float* __restrict__ w1,
                            const float* __restrict__ s_arr, const float* __restrict__ d_arr,
                            unsigned short* __restrict__ wm0, unsigned short* __restrict__ wm1) {
    const int cv = blockIdx.y;
    const int e  = blockIdx.x * 256 + threadIdx.x;       // 0 .. 4718591
    const float* w = cv ? w1 : w0;
    unsigned short* wm = cv ? wm1 : wm0;
    const int slab = e >> 13;            // 0..575  = ((b*8)+cc)*9 + t
    const int idx  = e & 8191;
    const int b  = slab / 72;
    const int s2 = slab - b * 72;
    const int cc = s2 / 9;
    const int t  = s2 - cc * 9;
    const int o  = idx >> 5;
    const int c5 = idx & 31;
    const int c  = cc * 32 + c5;
    const float val = w[((size_t)o * 256 + c) * 9 + t] * 0.029462782549439483f  // sqrt(2/2304)
                    * s_arr[(cv * 8 + b) * 256 + c] * d_arr[(cv * 8 + b) * 256 + o];
    wm[((size_t)slab << 13) + (c5 >> 3) * 2048 + o * 8 + (c5 & 7)] = f2bf(val);
}

// x (fp32 NCHW) -> xq (bf16 NHWC8): [b][g=32][h][w][8ch]; grid 32768, block 256
__global__ void convert_kernel(const float* __restrict__ x, unsigned short* __restrict__ xq) {
    const int blk = blockIdx.x;
    const int hh  = blk & 127;
    const int bg_ = blk >> 7;
    const int g   = bg_ & 31;
    const int b   = bg_ >> 5;
    __shared__ float sx[8][128];
    const int tid = threadIdx.x;
#pragma unroll
    for (int i = 0; i < 4; ++i) {
        const int idx = tid + i * 256;
        const int c8 = idx >> 7, p = idx & 127;
        sx[c8][p] = x[(((size_t)b * 256 + g * 8 + c8) * 128 + hh) * 128 + p];
    }
    __syncthreads();
    if (tid < 128) {
        const int p = tid;
        unsigned short u[8];
#pragma unroll
        for (int j = 0; j < 8; ++j) u[j] = f2bf(sx[j][p]);
        *(int4*)(xq + ((((size_t)b * 32 + g) * 128 + hh) * 128 + p) * 8) = pack8(u);
    }
}

// ---------------------------------------------------------------------------
// Modulated conv, implicit GEMM: M=256 (o), N=256 (2 rows x 128 px), K=2304.
// 16 waves (1024 thr), wave tile 64o x 64px, 4 waves/SIMD (R13 structure).
// NEW in R15: A-fragments load GLOBAL->VGPR per tap (no A in LDS at all) --
// LDS port traffic/tap drops 148KB->~68KB (B only); the 4x wm-duplication of
// A is absorbed by L1 (16KB slab fits 32KB L1). Three pipes (LDS-B, VMEM-A,
// MFMA) each ~1000cy/tap, overlapped by 4 desynced waves/SIMD.
// B single-buffered (4 rows), split-staged across barriers (R12-verified).
// All manual waits vmcnt(0) lgkmcnt(0). No setprio (R14: negative).
// Fused: +bias, leaky*sqrt2, PixelNorm; !FINAL_OUT -> NHWC8 bf16, else fp32 NCHW.
template<bool FINAL_OUT>
__global__ __launch_bounds__(1024, 4) void conv_kernel(
    const unsigned short* __restrict__ in_q, const unsigned short* __restrict__ wmod,
    const float* __restrict__ bias, const unsigned short* __restrict__ zpg,
    void* __restrict__ out_v) {

    // [0,32768)      B: 4 rows x 4 koct x 128 px x 16B (single buffer)
    // [32768,32832)  zero slot   [32832,33856) bias   [33856,37952) red
    // [0,65536)      reused by the NHWC8 transpose epilogue (after barrier)
    __shared__ __align__(16) char lds[65536];

    const int tid  = threadIdx.x;
    const int b    = blockIdx.x & 7;          // XCD-affine (image b -> XCD b)
    const int rp   = blockIdx.x >> 3;         // 0..63 row pair
    const int h0   = rp * 2;
    const int lane = tid & 63;
    const int wr   = tid >> 6;                // 0..15
    const int wm   = wr & 3;                  // o-quarter (64 o's)
    const int wn2  = (wr >> 2) & 1;           // px half
    const int wrow = wr >> 3;                 // row within pair
    const int l31  = lane & 31;
    const int khg  = lane >> 5;               // k-octet half

    float* sbias = (float*)(lds + 32832);
    if (tid < 256) sbias[tid] = bias[tid];
    if (tid < 4)   *(int4*)(lds + 32768 + tid * 16) = (int4){0, 0, 0, 0};

    // B frag lane bases (add (wrow+dy)*8192 + (dx-1)*16 per tap)
    int boff[2][2];
#pragma unroll
    for (int nb = 0; nb < 2; ++nb)
#pragma unroll
        for (int kh = 0; kh < 2; ++kh)
            boff[nb][kh] = (khg + 2 * kh) * 2048
                         + (wn2 * 64 + nb * 32 + l31) * 16;
    const bool isL = (wn2 == 0) && (l31 == 0);
    const bool isR = (wn2 == 1) && (l31 == 31);

    const unsigned short* wmb = wmod + (size_t)b * 589824;
    const unsigned short* xqb = in_q + (size_t)b * 4194304;   // [32][128][128][8]
    // per-lane A base: slab layout [koct][o][16B]; koct = khg + 2*kh
    const char* aLane = (const char*)wmb + khg * 4096 + (wm * 64 + l31) * 16;

    // A frags for one tap: global -> VGPR (compiler inserts the vmcnt waits)
    auto loadA = [&](int slab, short8 (&af)[2][2]) {
        const char* p = aLane + (size_t)slab * 16384;
        af[0][0] = *(const short8*)(p);            // mb0, kh0
        af[1][0] = *(const short8*)(p + 512);      // mb1 (+32 o)
        af[0][1] = *(const short8*)(p + 8192);     // kh1 (+2 koct)
        af[1][1] = *(const short8*)(p + 8704);
    };

    // stage B rows [r0, r1) of channel-block cc; wave wr>>2 owns row, wr&3 koct
    auto issueBrows = [&](int cc, int r0, int r1) {
        const int row = wr >> 2;              // 0..3 (wave-uniform)
        if (row < r0 || row >= r1) return;
        const int koct = wr & 3;
        char* dst = lds + row * 8192 + koct * 2048;
        const int hin = h0 - 1 + row;
        if ((unsigned)hin < 128u) {
            const unsigned short* src = xqb
                + ((size_t)(cc * 4 + koct) * 128 + hin) * 1024 + lane * 8;
            gld_lds16(src,       dst);
            gld_lds16(src + 512, dst + 1024);     // px + 64
        } else {
            gld_lds16(zpg, dst);
            gld_lds16(zpg, dst + 1024);
        }
    };

    f32x16 acc[2][2];
#pragma unroll
    for (int mb = 0; mb < 2; ++mb)
#pragma unroll
        for (int nb = 0; nb < 2; ++nb)
#pragma unroll
            for (int r = 0; r < 16; ++r) acc[mb][nb][r] = 0.f;

    // prologue: all 4 B rows of cc0; full drain via __syncthreads
    issueBrows(0, 0, 4);
    __syncthreads();

#pragma unroll 1
    for (int cc = 0; cc < 8; ++cc) {
#pragma unroll
        for (int r = 0; r < 3; ++r) {             // region = dy row = 3 taps
            const int g = cc * 3 + r;
            // top of r==0 (after cc-boundary barrier): rows 2,3 of THIS cc
            // (r==0 reads only rows 0,1 -> disjoint; drained at r==0's end).
            if (r == 0 && cc > 0) issueBrows(cc, 2, 4);
            // top of cc's LAST region: rows 0,1 of cc+1 (readers done at the
            // r==1-end barrier).
            if (r == 2 && cc < 7) issueBrows(cc + 1, 0, 2);
#pragma unroll
            for (int i = 0; i < 3; ++i) {         // tap: dx = i
                short8 af[2][2], bf[2][2];
                loadA(g * 3 + i, af);             // VMEM issue early
                const int badd = (wrow + r) * 8192 + (i - 1) * 16;
#pragma unroll
                for (int nb = 0; nb < 2; ++nb)
#pragma unroll
                    for (int kh = 0; kh < 2; ++kh) {
                        int off = boff[nb][kh] + badd;
                        if (i == 0 && nb == 0) off = isL ? 32768 : off;
                        if (i == 2 && nb == 1) off = isR ? 32768 : off;
                        bf[nb][kh] = *(const short8*)(lds + off);
                    }
#pragma unroll
                for (int kh = 0; kh < 2; ++kh)
#pragma unroll
                    for (int mb = 0; mb < 2; ++mb)
#pragma unroll
                        for (int nb = 0; nb < 2; ++nb)
                            acc[mb][nb] = __builtin_amdgcn_mfma_f32_32x32x16_bf16(
                                af[mb][kh], bf[nb][kh], acc[mb][nb], 0, 0, 0);
            }
            // region end: drain B staging (in flight under 24 MFMAs) + barrier
            asm volatile("s_waitcnt vmcnt(0) lgkmcnt(0)" ::: "memory");
            __builtin_amdgcn_sched_barrier(0);
            __builtin_amdgcn_s_barrier();
        }
    }

    // ---------------- epilogue: bias + leaky*sqrt2 + PixelNorm ----------------
    float psum[2] = {0.f, 0.f};
    const float actGain = 1.4142135623730951f;
#pragma unroll
    for (int mb = 0; mb < 2; ++mb)
#pragma unroll
        for (int rg = 0; rg < 16; ++rg) {
            const int row = (rg & 3) + 8 * (rg >> 2) + 4 * khg;
            const float bo = sbias[wm * 64 + mb * 32 + row];
#pragma unroll
            for (int nb = 0; nb < 2; ++nb) {
                float v = acc[mb][nb][rg] + bo;
                v = (v > 0.f ? v : 0.2f * v) * actGain;
                acc[mb][nb][rg] = v;
                psum[nb] += v * v;
            }
        }
    psum[0] += __shfl_xor(psum[0], 32);
    psum[1] += __shfl_xor(psum[1], 32);
    float* red = (float*)(lds + 33856);       // [(wrow*2+wn2)*4+wm][64 px]
    const int rslot = (wrow * 2 + wn2) * 4 + wm;
    if (lane < 32) {
        red[rslot * 64 + l31]      = psum[0];
        red[rslot * 64 + 32 + l31] = psum[1];
    }
    __syncthreads();
    float rs[2];
#pragma unroll
    for (int nb = 0; nb < 2; ++nb) {
        const int p = nb * 32 + l31;
        const int base = (wrow * 2 + wn2) * 4;
        const float ssum = red[(base + 0) * 64 + p] + red[(base + 1) * 64 + p]
                         + red[(base + 2) * 64 + p] + red[(base + 3) * 64 + p];
        rs[nb] = rsqrtf(ssum * (1.0f / 256.0f) + 1e-8f);
    }

    const int h = h0 + wrow;
    if (FINAL_OUT) {
        float* outF = (float*)out_v;
#pragma unroll
        for (int mb = 0; mb < 2; ++mb)
#pragma unroll
            for (int rg = 0; rg < 16; ++rg) {
                const int row = (rg & 3) + 8 * (rg >> 2) + 4 * khg;
                const int o = wm * 64 + mb * 32 + row;
                const size_t rb = (((size_t)b * 256 + o) * 128 + h) * 128 + wn2 * 64;
#pragma unroll
                for (int nb = 0; nb < 2; ++nb)
                    outF[rb + nb * 32 + l31] = acc[mb][nb][rg] * rs[nb];
            }
    } else {
        // per-wave transpose 64o x 64px -> NHWC8 bf16, fully unrolled (rule #20)
        __syncthreads();   // rs reads done; transpose region overlaps bias/red
        unsigned short* outB = (unsigned short*)out_v;
        char* wreg = lds + wr * 4096;         // [64 px][32 o] bf16, chunk-swizzled
#pragma unroll
        for (int mb = 0; mb < 2; ++mb) {
#pragma unroll
            for (int rg = 0; rg < 16; rg += 2) {
                const int row = (rg & 3) + 8 * (rg >> 2) + 4 * khg;   // even, 0..31
#pragma unroll
                for (int nb = 0; nb < 2; ++nb) {
                    const int pxl = nb * 32 + l31;
                    const unsigned lo = f2bf(acc[mb][nb][rg]     * rs[nb]);
                    const unsigned hi = f2bf(acc[mb][nb][rg + 1] * rs[nb]);
                    *(unsigned int*)(wreg + pxl * 64 + (((row >> 3) ^ (pxl & 3)) << 4)
                                     + (row & 7) * 2) = lo | (hi << 16);
                }
            }
            asm volatile("s_waitcnt lgkmcnt(0)" ::: "memory");
#pragma unroll
            for (int oc = 0; oc < 4; ++oc) {
                const int pxl = lane;
                const int4 v = *(const int4*)(wreg + pxl * 64 + ((oc ^ (pxl & 3)) << 4));
                const int gch = wm * 8 + mb * 4 + oc;
                *(int4*)(outB + ((((size_t)b * 32 + gch) * 128 + h) * 128
                                 + wn2 * 64 + pxl) * 8) = v;
            }
            asm volatile("s_waitcnt lgkmcnt(0)" ::: "memory");
        }
    }
}

// ---------------------------------------------------------------------------
extern "C" void kernel_launch(void* const* d_in, const int* in_sizes, int n_in,
                              void* d_out, int out_size, void* d_ws, size_t ws_size,
                              hipStream_t stream) {
    (void)in_sizes; (void)n_in; (void)out_size; (void)ws_size;
    const float* x      = (const float*)d_in[0];
    const float* latent = (const float*)d_in[1];
    const float* w0     = (const float*)d_in[2];
    const float* b0     = (const float*)d_in[3];
    const float* el0w   = (const float*)d_in[4];
    const float* el0b   = (const float*)d_in[5];
    const float* w1     = (const float*)d_in[6];
    const float* b1     = (const float*)d_in[7];
    const float* el1w   = (const float*)d_in[8];
    const float* el1b   = (const float*)d_in[9];

    char* ws = (char*)d_ws;
    float* s_arr = (float*)ws;                                   // 16 KB
    float* d_arr = (float*)(ws + 16384);                         // 16 KB
    float* wsq   = (float*)(ws + 32768);                         // 512 KB (reused as zero page)
    unsigned short* zpg = (unsigned short*)(ws + 32768);         // 256 B zeros (after demod)
    unsigned short* wm0 = (unsigned short*)(ws + 557056);        // 9.4 MB
    unsigned short* wm1 = (unsigned short*)(ws + 9994240);       // 9.4 MB
    unsigned short* xq  = (unsigned short*)(ws + 19431424);      // 67 MB
    unsigned short* tmp = (unsigned short*)(ws + 86540288);      // 67 MB

    style_kernel<<<16, 256, 0, stream>>>(latent, el0w, el0b, el1w, el1b, s_arr);
    wsq_kernel<<<512, 256, 0, stream>>>(w0, w1, wsq);
    demod_kernel<<<16, 256, 0, stream>>>(s_arr, wsq, d_arr);
    hipMemsetAsync(zpg, 0, 256, stream);   // wsq no longer needed; reuse as zero page
    fold_kernel<<<dim3(18432, 2), 256, 0, stream>>>(w0, w1, s_arr, d_arr, wm0, wm1);
    convert_kernel<<<32768, 256, 0, stream>>>(x, xq);

    conv_kernel<false><<<512, 1024, 0, stream>>>(xq, wm0, b0, zpg, tmp);
    conv_kernel<true><<<512, 1024, 0, stream>>>(tmp, wm1, b1, zpg, d_out);
}

// Round 16
// 364.216 us; speedup vs baseline: 1.0858x; 1.0827x over previous
//
#include <hip/hip_runtime.h>
#include <hip/hip_bf16.h>

typedef __attribute__((ext_vector_type(8))) short short8;
typedef __attribute__((ext_vector_type(16))) float f32x16;

typedef const __attribute__((address_space(1))) unsigned int* gas1_t;
typedef __attribute__((address_space(3))) unsigned int* las3_t;

__device__ __forceinline__ unsigned short f2bf(float x) {
    unsigned int u = __float_as_uint(x);
    u = (u + 0x7fffu + ((u >> 16) & 1u)) >> 16;   // RNE
    return (unsigned short)u;
}

__device__ __forceinline__ int4 pack8(const unsigned short* u) {
    int4 p;
    p.x = (int)((unsigned)u[0] | ((unsigned)u[1] << 16));
    p.y = (int)((unsigned)u[2] | ((unsigned)u[3] << 16));
    p.z = (int)((unsigned)u[4] | ((unsigned)u[5] << 16));
    p.w = (int)((unsigned)u[6] | ((unsigned)u[7] << 16));
    return p;
}

__device__ __forceinline__ void gld_lds16(const void* g, void* l) {
    __builtin_amdgcn_global_load_lds((gas1_t)g, (las3_t)l, 16, 0, 0);
}

// ---------------------------------------------------------------------------
// s[cv][b][c] = 1 + PixelNorm(EqualLinear(latent)); grid 16, block 256
__global__ void style_kernel(const float* __restrict__ latent,
                             const float* __restrict__ elw0, const float* __restrict__ elb0,
                             const float* __restrict__ elw1, const float* __restrict__ elb1,
                             float* __restrict__ s_arr) {
    const int cv = blockIdx.x >> 3;
    const int b  = blockIdx.x & 7;
    const int c  = threadIdx.x;
    const float* elw = cv ? elw1 : elw0;
    const float* elb = cv ? elb1 : elb0;

    __shared__ float lat[512];
    lat[c] = latent[b * 512 + c];
    lat[c + 256] = latent[b * 512 + c + 256];
    __syncthreads();

    float accv = 0.f;
    const float* wrow = elw + (size_t)c * 512;
#pragma unroll 8
    for (int k = 0; k < 512; ++k) accv += lat[k] * wrow[k];
    const float lin = accv * 0.04419417382415922f + elb[c];

    float sq = lin * lin;
#pragma unroll
    for (int off = 32; off >= 1; off >>= 1) sq += __shfl_xor(sq, off);
    __shared__ float wsum[4];
    if ((threadIdx.x & 63) == 0) wsum[threadIdx.x >> 6] = sq;
    __syncthreads();
    const float total = wsum[0] + wsum[1] + wsum[2] + wsum[3];
    const float s = 1.0f + lin * rsqrtf(total * (1.0f / 256.0f) + 1e-8f);
    s_arr[(cv * 8 + b) * 256 + c] = s;
}

// wsq[cv][o][c] = sum_t (w*sc)^2 ; grid 512, block 256
__global__ void wsq_kernel(const float* __restrict__ w0, const float* __restrict__ w1,
                           float* __restrict__ wsq) {
    const int cv = blockIdx.x >> 8;
    const int o  = blockIdx.x & 255;
    const int c  = threadIdx.x;
    const float* w = cv ? w1 : w0;
    const size_t base = ((size_t)o * 256 + c) * 9;
    float ssum = 0.f;
#pragma unroll
    for (int t = 0; t < 9; ++t) { float v = w[base + t]; ssum += v * v; }
    wsq[((size_t)cv * 256 + o) * 256 + c] = ssum * (2.0f / 2304.0f);
}

// d[cv][b][o] = rsqrt(sum_c s^2 * wsq + 1e-5) ; grid 16, block 256
__global__ void demod_kernel(const float* __restrict__ s_arr, const float* __restrict__ wsq,
                             float* __restrict__ d_arr) {
    const int cv = blockIdx.x >> 3;
    const int b  = blockIdx.x & 7;
    const int o  = threadIdx.x;
    __shared__ float ss[256];
    float sv = s_arr[(cv * 8 + b) * 256 + o];
    ss[o] = sv * sv;
    __syncthreads();
    const float* wrow = wsq + ((size_t)cv * 256 + o) * 256;
    float accv = 0.f;
#pragma unroll 8
    for (int c = 0; c < 256; ++c) accv += ss[c] * wrow[c];
    d_arr[(cv * 8 + b) * 256 + o] = rsqrtf(accv + 1e-5f);
}

// wmod[b][cc][t] slab (8192 elems) laid out [k-octet 0..3][o 0..255][8 ch]
// -> lane-contiguous 16B fragments. grid (18432,2), block 256
__global__ void fold_kernel(const float* __restrict__ w0, const float* __restrict__ w1,
                            const float* __restrict__ s_arr, const float* __restrict__ d_arr,
                            unsigned short* __restrict__ wm0, unsigned short* __restrict__ wm1) {
    const int cv = blockIdx.y;
    const int e  = blockIdx.x * 256 + threadIdx.x;       // 0 .. 4718591
    const float* w = cv ? w1 : w0;
    unsigned short* wm = cv ? wm1 : wm0;
    const int slab = e >> 13;            // 0..575  = ((b*8)+cc)*9 + t
    const int idx  = e & 8191;
    const int b  = slab / 72;
    const int s2 = slab - b * 72;
    const int cc = s2 / 9;
    const int t  = s2 - cc * 9;
    const int o  = idx >> 5;
    const int c5 = idx & 31;
    const int c  = cc * 32 + c5;
    const float val = w[((size_t)o * 256 + c) * 9 + t] * 0.029462782549439483f  // sqrt(2/2304)
                    * s_arr[(cv * 8 + b) * 256 + c] * d_arr[(cv * 8 + b) * 256 + o];
    wm[((size_t)slab << 13) + (c5 >> 3) * 2048 + o * 8 + (c5 & 7)] = f2bf(val);
}

// x (fp32 NCHW) -> xq (bf16 NHWC8): [b][g=32][h][w][8ch]; grid 32768, block 256
__global__ void convert_kernel(const float* __restrict__ x, unsigned short* __restrict__ xq) {
    const int blk = blockIdx.x;
    const int hh  = blk & 127;
    const int bg_ = blk >> 7;
    const int g   = bg_ & 31;
    const int b   = bg_ >> 5;
    __shared__ float sx[8][128];
    const int tid = threadIdx.x;
#pragma unroll
    for (int i = 0; i < 4; ++i) {
        const int idx = tid + i * 256;
        const int c8 = idx >> 7, p = idx & 127;
        sx[c8][p] = x[(((size_t)b * 256 + g * 8 + c8) * 128 + hh) * 128 + p];
    }
    __syncthreads();
    if (tid < 128) {
        const int p = tid;
        unsigned short u[8];
#pragma unroll
        for (int j = 0; j < 8; ++j) u[j] = f2bf(sx[j][p]);
        *(int4*)(xq + ((((size_t)b * 32 + g) * 128 + hh) * 128 + p) * 8) = pack8(u);
    }
}

// ---------------------------------------------------------------------------
// Modulated conv, implicit GEMM: M=256 (o), N=256 (2 rows x 128 px), K=2304.
// 8 waves, wave tile 64o x 128px. Region schedule (3 taps/barrier), A region-
// double-buffered via global_load_lds. NO setprio in the loop (R12/R14: it
// acts as a scheduling fence / starves loader waves). B staged split ACROSS
// BARRIERS: rows{0,1}(cc+1) at top of cc's last region; rows{2,3} of the
// CURRENT cc at top of r==0 (disjoint from r==0's reads; drained at r==0 end).
// All waits vmcnt(0) lgkmcnt(0) (unconditionally safe).
// BEST VERIFIED CONFIG (R12: 363.8us total, conv 146.5us, MfmaUtil 48.5%).
// Structural ceiling: per tap MFMA ~1033cy + LDS-port ~1150cy run at ~sum,
// and the register file (acc 128 + frags ~120 = 248/256) forbids the
// cross-tap frag double-banking needed to overlap them.
// Fused: +bias, leaky*sqrt2, PixelNorm; !FINAL_OUT -> NHWC8 bf16, else fp32 NCHW.
template<bool FINAL_OUT>
__global__ __launch_bounds__(512, 2) void conv_kernel(
    const unsigned short* __restrict__ in_q, const unsigned short* __restrict__ wmod,
    const float* __restrict__ bias, const unsigned short* __restrict__ zpg,
    void* __restrict__ out_v) {

    // [0,98304)       A: 2 region-buffers x 3 slabs x 16KB
    // [98304,131072)  B: 4 rows x 4 koct x 128 px x 16B (single buffer)
    // [131072,131136) zero slot   [131136,132160) bias   [132160,136256) red
    __shared__ __align__(16) char lds[136256];

    const int tid  = threadIdx.x;
    const int b    = blockIdx.x & 7;          // XCD-affine (image b -> XCD b)
    const int rp   = blockIdx.x >> 3;         // 0..63 row pair
    const int h0   = rp * 2;
    const int lane = tid & 63;
    const int wr   = tid >> 6;                // 0..7
    const int wm   = wr & 3;                  // o-quarter (64 o's)
    const int wn   = wr >> 2;                 // row within pair
    const int l31  = lane & 31;
    const int khg  = lane >> 5;               // k-octet half

    float* sbias = (float*)(lds + 131136);
    if (tid < 256) sbias[tid] = bias[tid];
    if (tid < 4)   *(int4*)(lds + 131072 + tid * 16) = (int4){0, 0, 0, 0};

    // A frag byte offsets within a slab: [koct][o][16B]
    int aoff[2][2];
#pragma unroll
    for (int mb = 0; mb < 2; ++mb)
#pragma unroll
        for (int kh = 0; kh < 2; ++kh)
            aoff[mb][kh] = ((khg + 2 * kh) * 256 + wm * 64 + mb * 32 + l31) * 16;

    const unsigned short* wmb = wmod + (size_t)b * 589824;
    const unsigned short* xqb = in_q + (size_t)b * 4194304;   // [32][128][128][8]

    // stage 3 slabs (one region, 48KB) into region buffer nbuf
    auto issueA3 = [&](const char* src, int nbuf) {
        char* db = lds + nbuf * 49152 + wr * 2048;           // wave-uniform base
        const char* s = src + wr * 2048 + lane * 16;
#pragma unroll
        for (int j = 0; j < 3; ++j) {
            gld_lds16(s + j * 16384,        db + j * 16384);
            gld_lds16(s + j * 16384 + 1024, db + j * 16384 + 1024);
        }
    };

    // stage B rows [r0, r1) of channel-block cc
    auto issueBrows = [&](int cc, int r0, int r1) {
        const int koct = tid >> 7;            // wave-uniform (wr>>1)
        const int px   = tid & 127;
#pragma unroll
        for (int r = 0; r < 4; ++r) {
            if (r < r0 || r >= r1) continue;
            const int hin = h0 - 1 + r;
            const unsigned short* src = ((unsigned)hin < 128u)
                ? xqb + (((size_t)(cc * 4 + koct) * 128 + hin) * 128 + px) * 8
                : zpg;
            gld_lds16(src, lds + 98304 + r * 8192 + koct * 2048 + (wr & 1) * 1024);
        }
    };

    f32x16 acc[2][4];
#pragma unroll
    for (int mb = 0; mb < 2; ++mb)
#pragma unroll
        for (int nb = 0; nb < 4; ++nb)
#pragma unroll
            for (int r = 0; r < 16; ++r) acc[mb][nb][r] = 0.f;

    // prologue: region 0 A + all 4 B rows of cc0; full drain via __syncthreads
    issueA3((const char*)wmb, 0);
    issueBrows(0, 0, 4);
    __syncthreads();

    const char* gA = (const char*)wmb + 49152;   // region 1 onward
#pragma unroll 1
    for (int cc = 0; cc < 8; ++cc) {
#pragma unroll
        for (int r = 0; r < 3; ++r) {             // region = dy row = 3 taps
            const int g = cc * 3 + r;
            // top of r==0 (after the cc-boundary barrier): rows 2,3 of THIS cc
            // (r==0 reads only rows 0,1 -> disjoint; drained at r==0's end).
            if (r == 0 && cc > 0) issueBrows(cc, 2, 4);
            // top of cc's LAST region: rows 0,1 of cc+1 (readers done at the
            // r==1-end barrier; rows 0,1 not read again until next cc).
            if (r == 2 && cc < 7) issueBrows(cc + 1, 0, 2);
            if (g < 23) { issueA3(gA, (g + 1) & 1); gA += 49152; }
            const char* Ac = lds + (g & 1) * 49152;
#pragma unroll
            for (int i = 0; i < 3; ++i) {         // tap: dx = i
                short8 af[2][2], bf[4][2];
#pragma unroll
                for (int mb = 0; mb < 2; ++mb)
#pragma unroll
                    for (int kh = 0; kh < 2; ++kh)
                        af[mb][kh] = *(const short8*)(Ac + i * 16384 + aoff[mb][kh]);
#pragma unroll
                for (int nb = 0; nb < 4; ++nb)
#pragma unroll
                    for (int kh = 0; kh < 2; ++kh) {
                        int off = 98304 + (wn + r) * 8192 + (khg + 2 * kh) * 2048
                                + (nb * 32 + l31 + i - 1) * 16;
                        if (i == 0 && nb == 0) off = (l31 == 0)  ? 131072 : off;
                        if (i == 2 && nb == 3) off = (l31 == 31) ? 131072 : off;
                        bf[nb][kh] = *(const short8*)(lds + off);
                    }
#pragma unroll
                for (int kh = 0; kh < 2; ++kh)
#pragma unroll
                    for (int mb = 0; mb < 2; ++mb)
#pragma unroll
                        for (int nb = 0; nb < 4; ++nb)
                            acc[mb][nb] = __builtin_amdgcn_mfma_f32_32x32x16_bf16(
                                af[mb][kh], bf[nb][kh], acc[mb][nb], 0, 0, 0);
            }
            // region end: full drain (A(g+1) and any B rows have been in
            // flight under this region's 48 MFMAs -> mostly free).
            asm volatile("s_waitcnt vmcnt(0) lgkmcnt(0)" ::: "memory");
            __builtin_amdgcn_sched_barrier(0);
            __builtin_amdgcn_s_barrier();
        }
    }

    // ---------------- epilogue: bias + leaky*sqrt2 + PixelNorm ----------------
    float psum[4] = {0.f, 0.f, 0.f, 0.f};
    const float actGain = 1.4142135623730951f;
#pragma unroll
    for (int mb = 0; mb < 2; ++mb)
#pragma unroll
        for (int rg = 0; rg < 16; ++rg) {
            const int row = (rg & 3) + 8 * (rg >> 2) + 4 * khg;
            const float bo = sbias[wm * 64 + mb * 32 + row];
#pragma unroll
            for (int nb = 0; nb < 4; ++nb) {
                float v = acc[mb][nb][rg] + bo;
                v = (v > 0.f ? v : 0.2f * v) * actGain;
                acc[mb][nb][rg] = v;
                psum[nb] += v * v;
            }
        }
#pragma unroll
    for (int nb = 0; nb < 4; ++nb) psum[nb] += __shfl_xor(psum[nb], 32);
    float* red = (float*)(lds + 132160);      // [wn][wm][128 px]
    if (lane < 32) {
#pragma unroll
        for (int nb = 0; nb < 4; ++nb)
            red[(wn * 4 + wm) * 128 + nb * 32 + l31] = psum[nb];
    }
    __syncthreads();
    float rs[4];
#pragma unroll
    for (int nb = 0; nb < 4; ++nb) {
        const int p = nb * 32 + l31;
        const float ssum = red[(wn * 4 + 0) * 128 + p] + red[(wn * 4 + 1) * 128 + p]
                         + red[(wn * 4 + 2) * 128 + p] + red[(wn * 4 + 3) * 128 + p];
        rs[nb] = rsqrtf(ssum * (1.0f / 256.0f) + 1e-8f);
    }

    const int h = h0 + wn;
    if (FINAL_OUT) {
        float* outF = (float*)out_v;
#pragma unroll
        for (int mb = 0; mb < 2; ++mb)
#pragma unroll
            for (int rg = 0; rg < 16; ++rg) {
                const int row = (rg & 3) + 8 * (rg >> 2) + 4 * khg;
                const int o = wm * 64 + mb * 32 + row;
                const size_t rb = (((size_t)b * 256 + o) * 128 + h) * 128;
#pragma unroll
                for (int nb = 0; nb < 4; ++nb)
                    outF[rb + nb * 32 + l31] = acc[mb][nb][rg] * rs[nb];
            }
    } else {
        // per-wave transpose 32o x 128px -> NHWC8 bf16, fully unrolled (rule #20)
        unsigned short* outB = (unsigned short*)out_v;
        char* wreg = lds + wr * 8192;         // [128 px][32 o] bf16, chunk-swizzled
#pragma unroll
        for (int mb = 0; mb < 2; ++mb) {
#pragma unroll
            for (int rg = 0; rg < 16; rg += 2) {
                const int row = (rg & 3) + 8 * (rg >> 2) + 4 * khg;   // even, 0..31
#pragma unroll
                for (int nb = 0; nb < 4; ++nb) {
                    const int pxl = nb * 32 + l31;
                    const unsigned lo = f2bf(acc[mb][nb][rg]     * rs[nb]);
                    const unsigned hi = f2bf(acc[mb][nb][rg + 1] * rs[nb]);
                    *(unsigned int*)(wreg + pxl * 64 + (((row >> 3) ^ (pxl & 3)) << 4)
                                     + (row & 7) * 2) = lo | (hi << 16);
                }
            }
            asm volatile("s_waitcnt lgkmcnt(0)" ::: "memory");
#pragma unroll
            for (int oc = 0; oc < 4; ++oc)
#pragma unroll
                for (int ph = 0; ph < 2; ++ph) {
                    const int pxl = ph * 64 + lane;
                    const int4 v = *(const int4*)(wreg + pxl * 64 + ((oc ^ (pxl & 3)) << 4));
                    const int g = wm * 8 + mb * 4 + oc;
                    *(int4*)(outB + ((((size_t)b * 32 + g) * 128 + h) * 128 + pxl) * 8) = v;
                }
            asm volatile("s_waitcnt lgkmcnt(0)" ::: "memory");
        }
    }
}

// ---------------------------------------------------------------------------
extern "C" void kernel_launch(void* const* d_in, const int* in_sizes, int n_in,
                              void* d_out, int out_size, void* d_ws, size_t ws_size,
                              hipStream_t stream) {
    (void)in_sizes; (void)n_in; (void)out_size; (void)ws_size;
    const float* x      = (const float*)d_in[0];
    const float* latent = (const float*)d_in[1];
    const float* w0     = (const float*)d_in[2];
    const float* b0     = (const float*)d_in[3];
    const float* el0w   = (const float*)d_in[4];
    const float* el0b   = (const float*)d_in[5];
    const float* w1     = (const float*)d_in[6];
    const float* b1     = (const float*)d_in[7];
    const float* el1w   = (const float*)d_in[8];
    const float* el1b   = (const float*)d_in[9];

    char* ws = (char*)d_ws;
    float* s_arr = (float*)ws;                                   // 16 KB
    float* d_arr = (float*)(ws + 16384);                         // 16 KB
    float* wsq   = (float*)(ws + 32768);                         // 512 KB (reused as zero page)
    unsigned short* zpg = (unsigned short*)(ws + 32768);         // 256 B zeros (after demod)
    unsigned short* wm0 = (unsigned short*)(ws + 557056);        // 9.4 MB
    unsigned short* wm1 = (unsigned short*)(ws + 9994240);       // 9.4 MB
    unsigned short* xq  = (unsigned short*)(ws + 19431424);      // 67 MB
    unsigned short* tmp = (unsigned short*)(ws + 86540288);      // 67 MB

    style_kernel<<<16, 256, 0, stream>>>(latent, el0w, el0b, el1w, el1b, s_arr);
    wsq_kernel<<<512, 256, 0, stream>>>(w0, w1, wsq);
    demod_kernel<<<16, 256, 0, stream>>>(s_arr, wsq, d_arr);
    hipMemsetAsync(zpg, 0, 256, stream);   // wsq no longer needed; reuse as zero page
    fold_kernel<<<dim3(18432, 2), 256, 0, stream>>>(w0, w1, s_arr, d_arr, wm0, wm1);
    convert_kernel<<<32768, 256, 0, stream>>>(x, xq);

    conv_kernel<false><<<512, 512, 0, stream>>>(xq, wm0, b0, zpg, tmp);
    conv_kernel<true><<<512, 512, 0, stream>>>(tmp, wm1, b1, zpg, d_out);
}